// Round 11
// baseline (499.807 us; speedup 1.0000x reference)
//
#include <hip/hip_runtime.h>
#include <math.h>

#define N_NODES 50000
#define N_EDGES 800000
#define NFEAT 512
#define NHID 256
#define NCODE 64
#define NCLASS 40
#define NCLS_PAD 48
#define NB_SCAN 196  // ceil(50000/256)

typedef __attribute__((ext_vector_type(8))) short short8;
typedef __attribute__((ext_vector_type(8))) unsigned short ushort8;
typedef __attribute__((ext_vector_type(4))) unsigned short ushort4v;
typedef __attribute__((ext_vector_type(4))) float floatx4;

__device__ inline unsigned short f2bf(float f) {
    unsigned u = __builtin_bit_cast(unsigned, f);
    u += 0x7fff + ((u >> 16) & 1);
    return (unsigned short)(u >> 16);
}
__device__ inline float bf2f(unsigned short h) {
    return __builtin_bit_cast(float, (unsigned)h << 16);
}

// ---------------- CSR build (by dst) ----------------
__global__ __launch_bounds__(256) void hist_kernel(const int* __restrict__ dst,
                                                   int* __restrict__ counts) {
    int t = blockIdx.x * 256 + threadIdx.x;
    if (t < N_EDGES) atomicAdd(&counts[dst[t]], 1);
}

// 3-phase device scan
__global__ __launch_bounds__(256) void scan_block_sums(const int* __restrict__ counts,
                                                       int* __restrict__ blockSums) {
    __shared__ int red[256];
    int t = threadIdx.x;
    int i = blockIdx.x * 256 + t;
    red[t] = (i < N_NODES) ? counts[i] : 0;
    __syncthreads();
#pragma unroll
    for (int off = 128; off > 0; off >>= 1) {
        if (t < off) red[t] += red[t + off];
        __syncthreads();
    }
    if (t == 0) blockSums[blockIdx.x] = red[0];
}

__global__ __launch_bounds__(256) void scan_block_offsets(const int* __restrict__ blockSums,
                                                          int* __restrict__ blockOffsets,
                                                          int* __restrict__ offsets) {
    __shared__ int s[256];
    int t = threadIdx.x;
    int v = (t < NB_SCAN) ? blockSums[t] : 0;
    s[t] = v;
    __syncthreads();
#pragma unroll
    for (int off = 1; off < 256; off <<= 1) {
        int x = (t >= off) ? s[t - off] : 0;
        __syncthreads();
        s[t] += x;
        __syncthreads();
    }
    if (t < NB_SCAN) blockOffsets[t] = s[t] - v;  // exclusive
    if (t == 255) offsets[N_NODES] = s[255];      // total = E
}

__global__ __launch_bounds__(256) void scan_final(const int* __restrict__ counts,
                                                  const int* __restrict__ blockOffsets,
                                                  int* __restrict__ offsets) {
    __shared__ int s[256];
    int t = threadIdx.x;
    int i = blockIdx.x * 256 + t;
    int v = (i < N_NODES) ? counts[i] : 0;
    s[t] = v;
    __syncthreads();
#pragma unroll
    for (int off = 1; off < 256; off <<= 1) {
        int x = (t >= off) ? s[t - off] : 0;
        __syncthreads();
        s[t] += x;
        __syncthreads();
    }
    if (i < N_NODES) offsets[i] = blockOffsets[blockIdx.x] + s[t] - v;  // exclusive
}

// scatter edges into dst-sorted order as packed (src, w_bits) int2
__global__ __launch_bounds__(256) void scatter_kernel(const int* __restrict__ dst,
                                                      const int* __restrict__ src,
                                                      const float* __restrict__ w,
                                                      const int* __restrict__ offsets,
                                                      int* __restrict__ cursor,
                                                      int2* __restrict__ edges) {
    int t = blockIdx.x * 256 + threadIdx.x;
    if (t < N_EDGES) {
        int d = dst[t];
        int pos = offsets[d] + atomicAdd(&cursor[d], 1);
        edges[pos] = make_int2(src[t], __builtin_bit_cast(int, w[t]));
    }
}

// ---------------- Fused weight prep: W1t / W2bt / W_mulvt / W_dect ----------------
__global__ __launch_bounds__(256) void wprep_kernel(const float* __restrict__ W1,
                                                    const float* __restrict__ W2,
                                                    const float* __restrict__ W_mu,
                                                    const float* __restrict__ W_lv,
                                                    const float* __restrict__ W_dec,
                                                    unsigned short* __restrict__ W1t,
                                                    unsigned short* __restrict__ W2bt,
                                                    unsigned short* __restrict__ W_mulvt,
                                                    unsigned short* __restrict__ W_dect) {
    int idx = blockIdx.x * 256 + threadIdx.x;
    if (idx < NFEAT * NHID) {
        int k = idx >> 8;
        int n = idx & 255;
        W1t[(size_t)n * NFEAT + k] = f2bf(W1[idx]);
    } else if (idx < NFEAT * NHID + NCLS_PAD * NFEAT) {
        int i2 = idx - NFEAT * NHID;
        int n = i2 >> 9;
        int k = i2 & 511;
        W2bt[i2] = (n < NCLASS) ? f2bf(W2[(size_t)k * NCLASS + n]) : (unsigned short)0;
    } else if (idx < NFEAT * NHID + NCLS_PAD * NFEAT + 128 * 256) {
        int i2 = idx - NFEAT * NHID - NCLS_PAD * NFEAT;
        int j = i2 >> 8;
        int k = i2 & 255;
        float v = (j < 64) ? W_mu[(size_t)k * NCODE + j] : W_lv[(size_t)k * NCODE + (j - 64)];
        W_mulvt[i2] = f2bf(v);
    } else if (idx < NFEAT * NHID + NCLS_PAD * NFEAT + 128 * 256 + 256 * 64) {
        int i2 = idx - NFEAT * NHID - NCLS_PAD * NFEAT - 128 * 256;
        int n = i2 >> 6;
        int k = i2 & 63;
        W_dect[i2] = f2bf(W_dec[(size_t)k * NHID + n]);
    }
}

// ---------------- GEMM1 (bf16 MFMA, barrier-free K-loop, LDS-resident B-panel) ----------------
// grid (782, 4): block = 64 rows x 64 cols. Whole 64-col B-panel (64x512 bf16 = 64KB)
// staged in LDS ONCE (one barrier); K-loop then streams A direct from global with
// zero barriers/vmcnt drains -> loads pipeline across MFMAs.
__global__ __launch_bounds__(256) void gemm1_mfma(const float* __restrict__ A,
                                                  const unsigned short* __restrict__ Bt,
                                                  unsigned short* __restrict__ C) {
    __shared__ unsigned short Bs[64][520];  // pitch 520: bank stride 4 -> 2-way (free)
    int t = threadIdx.x;
    int wave = t >> 6, lane = t & 63;
    int quad = lane >> 4, m16 = lane & 15;
    int m0 = blockIdx.x * 64;
    int n0 = blockIdx.y * 64;

    // ---- stage whole B panel: thread t loads col t>>2, k-range (t&3)*128..+128 ----
    {
        int col = t >> 2;
        int kq = (t & 3) * 128;
        const unsigned short* src = Bt + (size_t)(n0 + col) * NFEAT + kq;
#pragma unroll
        for (int j = 0; j < 16; j++) {
            *(ushort8*)&Bs[col][kq + j * 8] = *(const ushort8*)(src + j * 8);
        }
    }

    int arow = m0 + wave * 16 + m16;
    if (arow >= N_NODES) arow = N_NODES - 1;
    const float* Arow = A + (size_t)arow * NFEAT + quad * 8;

    floatx4 acc[4];
#pragma unroll
    for (int i = 0; i < 4; i++) acc[i] = (floatx4){0.f, 0.f, 0.f, 0.f};

    __syncthreads();  // the only barrier

#pragma unroll 4
    for (int c = 0; c < 16; c++) {
        float4 a0 = *(const float4*)(Arow + c * 32);
        float4 a1 = *(const float4*)(Arow + c * 32 + 4);
        ushort8 av;
        av[0] = f2bf(a0.x); av[1] = f2bf(a0.y); av[2] = f2bf(a0.z); av[3] = f2bf(a0.w);
        av[4] = f2bf(a1.x); av[5] = f2bf(a1.y); av[6] = f2bf(a1.z); av[7] = f2bf(a1.w);
        short8 afrag = __builtin_bit_cast(short8, av);
#pragma unroll
        for (int nt = 0; nt < 4; nt++) {
            short8 bfrag = *(const short8*)&Bs[nt * 16 + m16][c * 32 + quad * 8];
            acc[nt] = __builtin_amdgcn_mfma_f32_16x16x32_bf16(afrag, bfrag, acc[nt], 0, 0, 0);
        }
    }
#pragma unroll
    for (int nt = 0; nt < 4; nt++) {
        int col = n0 + nt * 16 + m16;
#pragma unroll
        for (int r = 0; r < 4; r++) {
            int row = m0 + wave * 16 + quad * 4 + r;
            if (row < N_NODES) C[(size_t)row * NHID + col] = f2bf(acc[nt][r]);
        }
    }
}

// ---------------- SpMM1 + bias + relu -> x1cat[:,256:512] (bf16) ----------------
__global__ __launch_bounds__(256) void spmm1_kernel(const int* __restrict__ offsets,
                                                    const int2* __restrict__ edges,
                                                    const unsigned short* __restrict__ S1b,
                                                    const float* __restrict__ b1,
                                                    unsigned short* __restrict__ x1cat) {
    int n = blockIdx.x * 4 + (threadIdx.x >> 6);
    int lane = threadIdx.x & 63;
    int beg = offsets[n], end = offsets[n + 1];
    float ax = 0.f, ay = 0.f, az = 0.f, aw = 0.f;
    int i = beg;
    for (; i + 4 <= end; i += 4) {
        int2 e0 = edges[i], e1 = edges[i + 1], e2 = edges[i + 2], e3 = edges[i + 3];
        float w0 = __builtin_bit_cast(float, e0.y);
        float w1 = __builtin_bit_cast(float, e1.y);
        float w2 = __builtin_bit_cast(float, e2.y);
        float w3 = __builtin_bit_cast(float, e3.y);
        ushort4v r0 = *(const ushort4v*)&S1b[(size_t)e0.x * NHID + lane * 4];
        ushort4v r1 = *(const ushort4v*)&S1b[(size_t)e1.x * NHID + lane * 4];
        ushort4v r2 = *(const ushort4v*)&S1b[(size_t)e2.x * NHID + lane * 4];
        ushort4v r3 = *(const ushort4v*)&S1b[(size_t)e3.x * NHID + lane * 4];
        ax += w0 * bf2f(r0[0]) + w1 * bf2f(r1[0]) + w2 * bf2f(r2[0]) + w3 * bf2f(r3[0]);
        ay += w0 * bf2f(r0[1]) + w1 * bf2f(r1[1]) + w2 * bf2f(r2[1]) + w3 * bf2f(r3[1]);
        az += w0 * bf2f(r0[2]) + w1 * bf2f(r1[2]) + w2 * bf2f(r2[2]) + w3 * bf2f(r3[2]);
        aw += w0 * bf2f(r0[3]) + w1 * bf2f(r1[3]) + w2 * bf2f(r2[3]) + w3 * bf2f(r3[3]);
    }
    for (; i < end; i++) {
        int2 e = edges[i];
        float ww = __builtin_bit_cast(float, e.y);
        ushort4v r = *(const ushort4v*)&S1b[(size_t)e.x * NHID + lane * 4];
        ax += ww * bf2f(r[0]); ay += ww * bf2f(r[1]);
        az += ww * bf2f(r[2]); aw += ww * bf2f(r[3]);
    }
    float4 bb = *(const float4*)&b1[lane * 4];
    ushort4v hb;
    hb[0] = f2bf(fmaxf(ax + bb.x, 0.f));
    hb[1] = f2bf(fmaxf(ay + bb.y, 0.f));
    hb[2] = f2bf(fmaxf(az + bb.z, 0.f));
    hb[3] = f2bf(fmaxf(aw + bb.w, 0.f));
    *(ushort4v*)&x1cat[(size_t)n * (2 * NHID) + NHID + lane * 4] = hb;
}

// ---------------- Fused MLP via MFMA: 16 nodes/block ----------------
__global__ __launch_bounds__(256) void mlp_mfma(const unsigned short* __restrict__ x1cat_ro,
                                                const float* __restrict__ eps,
                                                const float* __restrict__ b_mu,
                                                const float* __restrict__ b_lv,
                                                const unsigned short* __restrict__ W_mulvt,
                                                const float* __restrict__ b_dec,
                                                const unsigned short* __restrict__ W_dect,
                                                unsigned short* __restrict__ x1cat) {
    __shared__ float smulv[16][132];
    __shared__ unsigned short z_bf[16][72];
    int t = threadIdx.x;
    int wave = t >> 6, lane = t & 63;
    int quad = lane >> 4, m16 = lane & 15;
    int node0 = blockIdx.x * 16;

    // ---- phase A: mu||lv = h1 @ W_mulvt ----
    {
        floatx4 acc[2];
        acc[0] = (floatx4){0.f, 0.f, 0.f, 0.f};
        acc[1] = (floatx4){0.f, 0.f, 0.f, 0.f};
        const unsigned short* Abase =
            x1cat_ro + (size_t)(node0 + m16) * 512 + 256 + quad * 8;
        const unsigned short* Bb0 = W_mulvt + (size_t)(wave * 32 + m16) * 256 + quad * 8;
        const unsigned short* Bb1 = Bb0 + 16 * 256;
#pragma unroll
        for (int k0 = 0; k0 < 256; k0 += 32) {
            short8 afrag = *(const short8*)(Abase + k0);
            short8 bf0 = *(const short8*)(Bb0 + k0);
            short8 bf1 = *(const short8*)(Bb1 + k0);
            acc[0] = __builtin_amdgcn_mfma_f32_16x16x32_bf16(afrag, bf0, acc[0], 0, 0, 0);
            acc[1] = __builtin_amdgcn_mfma_f32_16x16x32_bf16(afrag, bf1, acc[1], 0, 0, 0);
        }
#pragma unroll
        for (int nt = 0; nt < 2; nt++) {
            int j = wave * 32 + nt * 16 + m16;
            float bias = (j < 64) ? b_mu[j] : b_lv[j - 64];
#pragma unroll
            for (int r = 0; r < 4; r++)
                smulv[quad * 4 + r][j] = acc[nt][r] + bias;
        }
    }
    __syncthreads();
    // ---- phase B: z = mu + eps*exp(lv) ----
#pragma unroll
    for (int r = 0; r < 4; r++) {
        int idx = t + r * 256;
        int n = idx >> 6, j = idx & 63;
        float z = smulv[n][j] + eps[(size_t)node0 * NCODE + idx] * expf(smulv[n][64 + j]);
        z_bf[n][j] = f2bf(z);
    }
    __syncthreads();
    // ---- phase C: x1 = relu(z @ W_dect + b_dec) ----
    {
        floatx4 acc[4];
#pragma unroll
        for (int i = 0; i < 4; i++) acc[i] = (floatx4){0.f, 0.f, 0.f, 0.f};
#pragma unroll
        for (int ks = 0; ks < 2; ks++) {
            int k0 = ks * 32;
            short8 afrag = *(const short8*)&z_bf[m16][k0 + quad * 8];
#pragma unroll
            for (int nt = 0; nt < 4; nt++) {
                int col = wave * 64 + nt * 16 + m16;
                short8 bfrag = *(const short8*)(W_dect + (size_t)col * 64 + k0 + quad * 8);
                acc[nt] = __builtin_amdgcn_mfma_f32_16x16x32_bf16(afrag, bfrag, acc[nt], 0, 0, 0);
            }
        }
#pragma unroll
        for (int nt = 0; nt < 4; nt++) {
            int col = wave * 64 + nt * 16 + m16;
            float bias = b_dec[col];
#pragma unroll
            for (int r = 0; r < 4; r++) {
                int node = node0 + quad * 4 + r;
                x1cat[(size_t)node * 512 + col] = f2bf(fmaxf(acc[nt][r] + bias, 0.f));
            }
        }
    }
}

// ---------------- GEMM2 (bf16 MFMA, LDS-staged, reg-prefetch): support2 = x1cat @ W2 ----------
__global__ __launch_bounds__(256) void gemm2_mfma(const unsigned short* __restrict__ Xb,
                                                  const unsigned short* __restrict__ Bt,
                                                  float* __restrict__ S2) {
    __shared__ unsigned short As[64][40];
    __shared__ unsigned short Bs[48][40];
    int t = threadIdx.x;
    int wave = t >> 6, lane = t & 63;
    int quad = lane >> 4, m16 = lane & 15;
    int m0 = blockIdx.x * 64;

    floatx4 acc[3];
#pragma unroll
    for (int i = 0; i < 3; i++) acc[i] = (floatx4){0.f, 0.f, 0.f, 0.f};

    int ar = t >> 2;
    int ako = (t & 3) * 8;
    int arow = m0 + ar;
    if (arow >= N_NODES) arow = N_NODES - 1;
    const unsigned short* Abase = Xb + (size_t)arow * NFEAT + ako;
    const unsigned short* Bbase = Bt + (size_t)(t >> 2) * NFEAT + ako;
    bool bload = (t >> 2) < NCLS_PAD;

    ushort8 a0 = *(const ushort8*)(Abase);
    ushort8 b0;
    if (bload) b0 = *(const ushort8*)(Bbase);

    for (int k0 = 0; k0 < NFEAT; k0 += 32) {
        __syncthreads();
        *(ushort8*)&As[ar][ako] = a0;
        if (bload) *(ushort8*)&Bs[t >> 2][ako] = b0;
        __syncthreads();
        int kn = (k0 + 32 < NFEAT) ? (k0 + 32) : k0;
        a0 = *(const ushort8*)(Abase + kn);
        if (bload) b0 = *(const ushort8*)(Bbase + kn);
        short8 afrag = *(const short8*)&As[wave * 16 + m16][quad * 8];
#pragma unroll
        for (int nt = 0; nt < 3; nt++) {
            short8 bfrag = *(const short8*)&Bs[nt * 16 + m16][quad * 8];
            acc[nt] = __builtin_amdgcn_mfma_f32_16x16x32_bf16(afrag, bfrag, acc[nt], 0, 0, 0);
        }
    }
#pragma unroll
    for (int nt = 0; nt < 3; nt++) {
        int col = nt * 16 + m16;
        if (col < NCLASS) {
#pragma unroll
            for (int r = 0; r < 4; r++) {
                int row = m0 + wave * 16 + quad * 4 + r;
                if (row < N_NODES) S2[(size_t)row * NCLASS + col] = acc[nt][r];
            }
        }
    }
}

// ---------------- SpMM2 + bias + log_softmax -> out ----------------
__global__ __launch_bounds__(256) void spmm2_softmax_kernel(const int* __restrict__ offsets,
                                                            const int2* __restrict__ edges,
                                                            const float* __restrict__ S2,
                                                            const float* __restrict__ b2,
                                                            float* __restrict__ out) {
    int wave = threadIdx.x >> 6;
    int lane = threadIdx.x & 63;
    int n = blockIdx.x * 4 + wave;
    int beg = offsets[n], end = offsets[n + 1];
    float acc = 0.f;
    int i = beg;
    for (; i + 4 <= end; i += 4) {
        int2 e0 = edges[i], e1 = edges[i + 1], e2 = edges[i + 2], e3 = edges[i + 3];
        float w0 = __builtin_bit_cast(float, e0.y);
        float w1 = __builtin_bit_cast(float, e1.y);
        float w2 = __builtin_bit_cast(float, e2.y);
        float w3 = __builtin_bit_cast(float, e3.y);
        if (lane < NCLASS) {
            float v0 = S2[(size_t)e0.x * NCLASS + lane];
            float v1 = S2[(size_t)e1.x * NCLASS + lane];
            float v2 = S2[(size_t)e2.x * NCLASS + lane];
            float v3 = S2[(size_t)e3.x * NCLASS + lane];
            acc += w0 * v0 + w1 * v1 + w2 * v2 + w3 * v3;
        }
    }
    for (; i < end; i++) {
        int2 e = edges[i];
        float ww = __builtin_bit_cast(float, e.y);
        if (lane < NCLASS) acc += ww * S2[(size_t)e.x * NCLASS + lane];
    }
    float v = (lane < NCLASS) ? (acc + b2[lane]) : -INFINITY;
    float m = v;
#pragma unroll
    for (int off = 32; off > 0; off >>= 1) m = fmaxf(m, __shfl_xor(m, off));
    float ex = (lane < NCLASS) ? expf(v - m) : 0.f;
    float ssum = ex;
#pragma unroll
    for (int off = 32; off > 0; off >>= 1) ssum += __shfl_xor(ssum, off);
    if (lane < NCLASS) out[(size_t)n * NCLASS + lane] = v - m - logf(ssum);
}

extern "C" void kernel_launch(void* const* d_in, const int* in_sizes, int n_in,
                              void* d_out, int out_size, void* d_ws, size_t ws_size,
                              hipStream_t stream) {
    const float* x     = (const float*)d_in[0];
    const int*   esrc  = (const int*)d_in[1];
    const int*   edst  = (const int*)d_in[2];
    const float* ew    = (const float*)d_in[3];
    const float* eps   = (const float*)d_in[4];
    const float* W1    = (const float*)d_in[5];
    const float* b1    = (const float*)d_in[6];
    const float* W_mu  = (const float*)d_in[7];
    const float* b_mu  = (const float*)d_in[8];
    const float* W_lv  = (const float*)d_in[9];
    const float* b_lv  = (const float*)d_in[10];
    const float* W_dec = (const float*)d_in[11];
    const float* b_dec = (const float*)d_in[12];
    const float* W2    = (const float*)d_in[13];
    const float* b2    = (const float*)d_in[14];
    float* out = (float*)d_out;

    // workspace layout (counts & cursor adjacent -> single memset)
    unsigned short* support1b = (unsigned short*)d_ws;                     // 12.8M u16
    unsigned short* x1cat = support1b + (size_t)N_NODES * NHID;            // 25.6M u16
    float* support2 = (float*)(x1cat + (size_t)N_NODES * 2 * NHID);        // 2M f32
    unsigned short* W1t    = (unsigned short*)(support2 + (size_t)N_NODES * NCLASS);
    unsigned short* W2bt   = W1t + (size_t)NHID * NFEAT;
    unsigned short* W_mulvt = W2bt + (size_t)NCLS_PAD * NFEAT;
    unsigned short* W_dect  = W_mulvt + 128 * 256;
    int*   counts   = (int*)(W_dect + 256 * 64);
    int*   cursor   = counts + N_NODES;
    int*   offsets  = cursor + N_NODES;     // N+1
    int*   blockSums    = offsets + N_NODES + 1;   // NB_SCAN
    int*   blockOffsets = blockSums + NB_SCAN;     // NB_SCAN
    int2*  edges    = (int2*)(blockOffsets + NB_SCAN);
    edges = (int2*)(((size_t)edges + 7) & ~(size_t)7);
    size_t need = (size_t)((char*)(edges + N_EDGES) - (char*)d_ws);
    if (ws_size < need) return;

    hipMemsetAsync(counts, 0, 2 * N_NODES * sizeof(int), stream);  // counts + cursor
    hist_kernel<<<(N_EDGES + 255) / 256, 256, 0, stream>>>(edst, counts);
    scan_block_sums<<<NB_SCAN, 256, 0, stream>>>(counts, blockSums);
    scan_block_offsets<<<1, 256, 0, stream>>>(blockSums, blockOffsets, offsets);
    scan_final<<<NB_SCAN, 256, 0, stream>>>(counts, blockOffsets, offsets);
    scatter_kernel<<<(N_EDGES + 255) / 256, 256, 0, stream>>>(edst, esrc, ew, offsets, cursor,
                                                              edges);

    wprep_kernel<<<800, 256, 0, stream>>>(W1, W2, W_mu, W_lv, W_dec, W1t, W2bt, W_mulvt, W_dect);
    dim3 g1((N_NODES + 63) / 64, 4);
    gemm1_mfma<<<g1, 256, 0, stream>>>(x, W1t, support1b);
    spmm1_kernel<<<N_NODES / 4, 256, 0, stream>>>(offsets, edges, support1b, b1, x1cat);
    mlp_mfma<<<N_NODES / 16, 256, 0, stream>>>(x1cat, eps, b_mu, b_lv, W_mulvt, b_dec, W_dect,
                                               x1cat);
    gemm2_mfma<<<(N_NODES + 63) / 64, 256, 0, stream>>>(x1cat, W2bt, support2);
    spmm2_softmax_kernel<<<N_NODES / 4, 256, 0, stream>>>(offsets, edges, support2, b2, out);
}

// Round 12
// 454.556 us; speedup vs baseline: 1.0996x; 1.0996x over previous
//
#include <hip/hip_runtime.h>
#include <math.h>

#define N_NODES 50000
#define N_EDGES 800000
#define NFEAT 512
#define NHID 256
#define NCODE 64
#define NCLASS 40
#define NCLS_PAD 48
#define NB_SCAN 196  // ceil(50000/256)

typedef __attribute__((ext_vector_type(8))) short short8;
typedef __attribute__((ext_vector_type(8))) unsigned short ushort8;
typedef __attribute__((ext_vector_type(4))) unsigned short ushort4v;
typedef __attribute__((ext_vector_type(4))) float floatx4;

__device__ inline unsigned short f2bf(float f) {
    unsigned u = __builtin_bit_cast(unsigned, f);
    u += 0x7fff + ((u >> 16) & 1);
    return (unsigned short)(u >> 16);
}
__device__ inline float bf2f(unsigned short h) {
    return __builtin_bit_cast(float, (unsigned)h << 16);
}

// ---------------- CSR build (by dst) ----------------
__global__ __launch_bounds__(256) void hist_kernel(const int* __restrict__ dst,
                                                   int* __restrict__ counts) {
    int t = blockIdx.x * 256 + threadIdx.x;
    if (t < N_EDGES) atomicAdd(&counts[dst[t]], 1);
}

// 3-phase device scan
__global__ __launch_bounds__(256) void scan_block_sums(const int* __restrict__ counts,
                                                       int* __restrict__ blockSums) {
    __shared__ int red[256];
    int t = threadIdx.x;
    int i = blockIdx.x * 256 + t;
    red[t] = (i < N_NODES) ? counts[i] : 0;
    __syncthreads();
#pragma unroll
    for (int off = 128; off > 0; off >>= 1) {
        if (t < off) red[t] += red[t + off];
        __syncthreads();
    }
    if (t == 0) blockSums[blockIdx.x] = red[0];
}

__global__ __launch_bounds__(256) void scan_block_offsets(const int* __restrict__ blockSums,
                                                          int* __restrict__ blockOffsets,
                                                          int* __restrict__ offsets) {
    __shared__ int s[256];
    int t = threadIdx.x;
    int v = (t < NB_SCAN) ? blockSums[t] : 0;
    s[t] = v;
    __syncthreads();
#pragma unroll
    for (int off = 1; off < 256; off <<= 1) {
        int x = (t >= off) ? s[t - off] : 0;
        __syncthreads();
        s[t] += x;
        __syncthreads();
    }
    if (t < NB_SCAN) blockOffsets[t] = s[t] - v;  // exclusive
    if (t == 255) offsets[N_NODES] = s[255];      // total = E
}

__global__ __launch_bounds__(256) void scan_final(const int* __restrict__ counts,
                                                  const int* __restrict__ blockOffsets,
                                                  int* __restrict__ offsets) {
    __shared__ int s[256];
    int t = threadIdx.x;
    int i = blockIdx.x * 256 + t;
    int v = (i < N_NODES) ? counts[i] : 0;
    s[t] = v;
    __syncthreads();
#pragma unroll
    for (int off = 1; off < 256; off <<= 1) {
        int x = (t >= off) ? s[t - off] : 0;
        __syncthreads();
        s[t] += x;
        __syncthreads();
    }
    if (i < N_NODES) offsets[i] = blockOffsets[blockIdx.x] + s[t] - v;  // exclusive
}

// scatter edges into dst-sorted order as packed (src, w_bits) int2
__global__ __launch_bounds__(256) void scatter_kernel(const int* __restrict__ dst,
                                                      const int* __restrict__ src,
                                                      const float* __restrict__ w,
                                                      const int* __restrict__ offsets,
                                                      int* __restrict__ cursor,
                                                      int2* __restrict__ edges) {
    int t = blockIdx.x * 256 + threadIdx.x;
    if (t < N_EDGES) {
        int d = dst[t];
        int pos = offsets[d] + atomicAdd(&cursor[d], 1);
        edges[pos] = make_int2(src[t], __builtin_bit_cast(int, w[t]));
    }
}

// ---------------- Fused weight prep: W1t / W2bt / W_mulvt / W_dect ----------------
__global__ __launch_bounds__(256) void wprep_kernel(const float* __restrict__ W1,
                                                    const float* __restrict__ W2,
                                                    const float* __restrict__ W_mu,
                                                    const float* __restrict__ W_lv,
                                                    const float* __restrict__ W_dec,
                                                    unsigned short* __restrict__ W1t,
                                                    unsigned short* __restrict__ W2bt,
                                                    unsigned short* __restrict__ W_mulvt,
                                                    unsigned short* __restrict__ W_dect) {
    int idx = blockIdx.x * 256 + threadIdx.x;
    if (idx < NFEAT * NHID) {
        int k = idx >> 8;
        int n = idx & 255;
        W1t[(size_t)n * NFEAT + k] = f2bf(W1[idx]);
    } else if (idx < NFEAT * NHID + NCLS_PAD * NFEAT) {
        int i2 = idx - NFEAT * NHID;
        int n = i2 >> 9;
        int k = i2 & 511;
        W2bt[i2] = (n < NCLASS) ? f2bf(W2[(size_t)k * NCLASS + n]) : (unsigned short)0;
    } else if (idx < NFEAT * NHID + NCLS_PAD * NFEAT + 128 * 256) {
        int i2 = idx - NFEAT * NHID - NCLS_PAD * NFEAT;
        int j = i2 >> 8;
        int k = i2 & 255;
        float v = (j < 64) ? W_mu[(size_t)k * NCODE + j] : W_lv[(size_t)k * NCODE + (j - 64)];
        W_mulvt[i2] = f2bf(v);
    } else if (idx < NFEAT * NHID + NCLS_PAD * NFEAT + 128 * 256 + 256 * 64) {
        int i2 = idx - NFEAT * NHID - NCLS_PAD * NFEAT - 128 * 256;
        int n = i2 >> 6;
        int k = i2 & 63;
        W_dect[i2] = f2bf(W_dec[(size_t)k * NHID + n]);
    }
}

// ---------------- GEMM1 (bf16 MFMA, 64x128 tile, BK=64): support1b = bf16(x @ W1) ------------
// r10 config: best measured point (63.8 us, ~126 MB @ ~2 TB/s). Barrier variants all worse.
__global__ __launch_bounds__(256) void gemm1_mfma(const float* __restrict__ A,
                                                  const unsigned short* __restrict__ Bt,
                                                  unsigned short* __restrict__ C) {
    __shared__ unsigned short As[64][72];
    __shared__ unsigned short Bs[128][72];
    int t = threadIdx.x;
    int wave = t >> 6, lane = t & 63;
    int quad = lane >> 4, m16 = lane & 15;
    int m0 = blockIdx.x * 64;
    int n0 = blockIdx.y * 128;

    floatx4 acc[8];
#pragma unroll
    for (int i = 0; i < 8; i++) acc[i] = (floatx4){0.f, 0.f, 0.f, 0.f};

    int ar = t >> 2;
    int ako = (t & 3) * 16;
    int arow = m0 + ar;
    if (arow >= N_NODES) arow = N_NODES - 1;
    const float* Abase = A + (size_t)arow * NFEAT + ako;

    int bcol = t >> 1;
    int bko = (t & 1) * 32;
    const unsigned short* Bbase = Bt + (size_t)(n0 + bcol) * NFEAT + bko;

    for (int k0 = 0; k0 < NFEAT; k0 += 64) {
        float4 a0 = *(const float4*)(Abase + k0);
        float4 a1 = *(const float4*)(Abase + k0 + 4);
        float4 a2 = *(const float4*)(Abase + k0 + 8);
        float4 a3 = *(const float4*)(Abase + k0 + 12);
        ushort8 b0 = *(const ushort8*)(Bbase + k0);
        ushort8 b1 = *(const ushort8*)(Bbase + k0 + 8);
        ushort8 b2 = *(const ushort8*)(Bbase + k0 + 16);
        ushort8 b3 = *(const ushort8*)(Bbase + k0 + 24);
        __syncthreads();
        ushort8 av0, av1;
        av0[0] = f2bf(a0.x); av0[1] = f2bf(a0.y); av0[2] = f2bf(a0.z); av0[3] = f2bf(a0.w);
        av0[4] = f2bf(a1.x); av0[5] = f2bf(a1.y); av0[6] = f2bf(a1.z); av0[7] = f2bf(a1.w);
        av1[0] = f2bf(a2.x); av1[1] = f2bf(a2.y); av1[2] = f2bf(a2.z); av1[3] = f2bf(a2.w);
        av1[4] = f2bf(a3.x); av1[5] = f2bf(a3.y); av1[6] = f2bf(a3.z); av1[7] = f2bf(a3.w);
        *(ushort8*)&As[ar][ako] = av0;
        *(ushort8*)&As[ar][ako + 8] = av1;
        *(ushort8*)&Bs[bcol][bko] = b0;
        *(ushort8*)&Bs[bcol][bko + 8] = b1;
        *(ushort8*)&Bs[bcol][bko + 16] = b2;
        *(ushort8*)&Bs[bcol][bko + 24] = b3;
        __syncthreads();
#pragma unroll
        for (int c = 0; c < 2; c++) {
            short8 afrag = *(const short8*)&As[wave * 16 + m16][c * 32 + quad * 8];
#pragma unroll
            for (int nt = 0; nt < 8; nt++) {
                short8 bfrag = *(const short8*)&Bs[nt * 16 + m16][c * 32 + quad * 8];
                acc[nt] = __builtin_amdgcn_mfma_f32_16x16x32_bf16(afrag, bfrag, acc[nt], 0, 0, 0);
            }
        }
    }
#pragma unroll
    for (int nt = 0; nt < 8; nt++) {
        int col = n0 + nt * 16 + m16;
#pragma unroll
        for (int r = 0; r < 4; r++) {
            int row = m0 + wave * 16 + quad * 4 + r;
            if (row < N_NODES) C[(size_t)row * NHID + col] = f2bf(acc[nt][r]);
        }
    }
}

// ---------------- SpMM1 + bias + relu -> x1cat[:,256:512] (bf16), 8-edge unroll --------------
__global__ __launch_bounds__(256) void spmm1_kernel(const int* __restrict__ offsets,
                                                    const int2* __restrict__ edges,
                                                    const unsigned short* __restrict__ S1b,
                                                    const float* __restrict__ b1,
                                                    unsigned short* __restrict__ x1cat) {
    int n = blockIdx.x * 4 + (threadIdx.x >> 6);
    int lane = threadIdx.x & 63;
    int beg = offsets[n], end = offsets[n + 1];
    float ax = 0.f, ay = 0.f, az = 0.f, aw = 0.f;
    int i = beg;
    for (; i + 8 <= end; i += 8) {
        int2 e[8];
        ushort4v r[8];
#pragma unroll
        for (int u = 0; u < 8; u++) e[u] = edges[i + u];
#pragma unroll
        for (int u = 0; u < 8; u++)
            r[u] = *(const ushort4v*)&S1b[(size_t)e[u].x * NHID + lane * 4];
#pragma unroll
        for (int u = 0; u < 8; u++) {
            float ww = __builtin_bit_cast(float, e[u].y);
            ax += ww * bf2f(r[u][0]);
            ay += ww * bf2f(r[u][1]);
            az += ww * bf2f(r[u][2]);
            aw += ww * bf2f(r[u][3]);
        }
    }
    for (; i < end; i++) {
        int2 e = edges[i];
        float ww = __builtin_bit_cast(float, e.y);
        ushort4v r = *(const ushort4v*)&S1b[(size_t)e.x * NHID + lane * 4];
        ax += ww * bf2f(r[0]); ay += ww * bf2f(r[1]);
        az += ww * bf2f(r[2]); aw += ww * bf2f(r[3]);
    }
    float4 bb = *(const float4*)&b1[lane * 4];
    ushort4v hb;
    hb[0] = f2bf(fmaxf(ax + bb.x, 0.f));
    hb[1] = f2bf(fmaxf(ay + bb.y, 0.f));
    hb[2] = f2bf(fmaxf(az + bb.z, 0.f));
    hb[3] = f2bf(fmaxf(aw + bb.w, 0.f));
    *(ushort4v*)&x1cat[(size_t)n * (2 * NHID) + NHID + lane * 4] = hb;
}

// ---------------- Fused MLP via MFMA: 16 nodes/block ----------------
__global__ __launch_bounds__(256) void mlp_mfma(const unsigned short* __restrict__ x1cat_ro,
                                                const float* __restrict__ eps,
                                                const float* __restrict__ b_mu,
                                                const float* __restrict__ b_lv,
                                                const unsigned short* __restrict__ W_mulvt,
                                                const float* __restrict__ b_dec,
                                                const unsigned short* __restrict__ W_dect,
                                                unsigned short* __restrict__ x1cat) {
    __shared__ float smulv[16][132];
    __shared__ unsigned short z_bf[16][72];
    int t = threadIdx.x;
    int wave = t >> 6, lane = t & 63;
    int quad = lane >> 4, m16 = lane & 15;
    int node0 = blockIdx.x * 16;

    // ---- phase A: mu||lv = h1 @ W_mulvt ----
    {
        floatx4 acc[2];
        acc[0] = (floatx4){0.f, 0.f, 0.f, 0.f};
        acc[1] = (floatx4){0.f, 0.f, 0.f, 0.f};
        const unsigned short* Abase =
            x1cat_ro + (size_t)(node0 + m16) * 512 + 256 + quad * 8;
        const unsigned short* Bb0 = W_mulvt + (size_t)(wave * 32 + m16) * 256 + quad * 8;
        const unsigned short* Bb1 = Bb0 + 16 * 256;
#pragma unroll
        for (int k0 = 0; k0 < 256; k0 += 32) {
            short8 afrag = *(const short8*)(Abase + k0);
            short8 bf0 = *(const short8*)(Bb0 + k0);
            short8 bf1 = *(const short8*)(Bb1 + k0);
            acc[0] = __builtin_amdgcn_mfma_f32_16x16x32_bf16(afrag, bf0, acc[0], 0, 0, 0);
            acc[1] = __builtin_amdgcn_mfma_f32_16x16x32_bf16(afrag, bf1, acc[1], 0, 0, 0);
        }
#pragma unroll
        for (int nt = 0; nt < 2; nt++) {
            int j = wave * 32 + nt * 16 + m16;
            float bias = (j < 64) ? b_mu[j] : b_lv[j - 64];
#pragma unroll
            for (int r = 0; r < 4; r++)
                smulv[quad * 4 + r][j] = acc[nt][r] + bias;
        }
    }
    __syncthreads();
    // ---- phase B: z = mu + eps*exp(lv) ----
#pragma unroll
    for (int r = 0; r < 4; r++) {
        int idx = t + r * 256;
        int n = idx >> 6, j = idx & 63;
        float z = smulv[n][j] + eps[(size_t)node0 * NCODE + idx] * expf(smulv[n][64 + j]);
        z_bf[n][j] = f2bf(z);
    }
    __syncthreads();
    // ---- phase C: x1 = relu(z @ W_dect + b_dec) ----
    {
        floatx4 acc[4];
#pragma unroll
        for (int i = 0; i < 4; i++) acc[i] = (floatx4){0.f, 0.f, 0.f, 0.f};
#pragma unroll
        for (int ks = 0; ks < 2; ks++) {
            int k0 = ks * 32;
            short8 afrag = *(const short8*)&z_bf[m16][k0 + quad * 8];
#pragma unroll
            for (int nt = 0; nt < 4; nt++) {
                int col = wave * 64 + nt * 16 + m16;
                short8 bfrag = *(const short8*)(W_dect + (size_t)col * 64 + k0 + quad * 8);
                acc[nt] = __builtin_amdgcn_mfma_f32_16x16x32_bf16(afrag, bfrag, acc[nt], 0, 0, 0);
            }
        }
#pragma unroll
        for (int nt = 0; nt < 4; nt++) {
            int col = wave * 64 + nt * 16 + m16;
            float bias = b_dec[col];
#pragma unroll
            for (int r = 0; r < 4; r++) {
                int node = node0 + quad * 4 + r;
                x1cat[(size_t)node * 512 + col] = f2bf(fmaxf(acc[nt][r] + bias, 0.f));
            }
        }
    }
}

// ---------------- GEMM2 (bf16 MFMA, LDS-staged, reg-prefetch): S2b = bf16(x1cat @ W2) --------
__global__ __launch_bounds__(256) void gemm2_mfma(const unsigned short* __restrict__ Xb,
                                                  const unsigned short* __restrict__ Bt,
                                                  unsigned short* __restrict__ S2b) {
    __shared__ unsigned short As[64][40];
    __shared__ unsigned short Bs[48][40];
    int t = threadIdx.x;
    int wave = t >> 6, lane = t & 63;
    int quad = lane >> 4, m16 = lane & 15;
    int m0 = blockIdx.x * 64;

    floatx4 acc[3];
#pragma unroll
    for (int i = 0; i < 3; i++) acc[i] = (floatx4){0.f, 0.f, 0.f, 0.f};

    int ar = t >> 2;
    int ako = (t & 3) * 8;
    int arow = m0 + ar;
    if (arow >= N_NODES) arow = N_NODES - 1;
    const unsigned short* Abase = Xb + (size_t)arow * NFEAT + ako;
    const unsigned short* Bbase = Bt + (size_t)(t >> 2) * NFEAT + ako;
    bool bload = (t >> 2) < NCLS_PAD;

    ushort8 a0 = *(const ushort8*)(Abase);
    ushort8 b0;
    if (bload) b0 = *(const ushort8*)(Bbase);

    for (int k0 = 0; k0 < NFEAT; k0 += 32) {
        __syncthreads();
        *(ushort8*)&As[ar][ako] = a0;
        if (bload) *(ushort8*)&Bs[t >> 2][ako] = b0;
        __syncthreads();
        int kn = (k0 + 32 < NFEAT) ? (k0 + 32) : k0;
        a0 = *(const ushort8*)(Abase + kn);
        if (bload) b0 = *(const ushort8*)(Bbase + kn);
        short8 afrag = *(const short8*)&As[wave * 16 + m16][quad * 8];
#pragma unroll
        for (int nt = 0; nt < 3; nt++) {
            short8 bfrag = *(const short8*)&Bs[nt * 16 + m16][quad * 8];
            acc[nt] = __builtin_amdgcn_mfma_f32_16x16x32_bf16(afrag, bfrag, acc[nt], 0, 0, 0);
        }
    }
#pragma unroll
    for (int nt = 0; nt < 3; nt++) {
        int col = nt * 16 + m16;
        if (col < NCLASS) {
#pragma unroll
            for (int r = 0; r < 4; r++) {
                int row = m0 + wave * 16 + quad * 4 + r;
                if (row < N_NODES) S2b[(size_t)row * NCLASS + col] = f2bf(acc[nt][r]);
            }
        }
    }
}

// ---------------- SpMM2 (bf16 gather) + bias + log_softmax -> out ----------------
__global__ __launch_bounds__(256) void spmm2_softmax_kernel(const int* __restrict__ offsets,
                                                            const int2* __restrict__ edges,
                                                            const unsigned short* __restrict__ S2b,
                                                            const float* __restrict__ b2,
                                                            float* __restrict__ out) {
    int wave = threadIdx.x >> 6;
    int lane = threadIdx.x & 63;
    int n = blockIdx.x * 4 + wave;
    int beg = offsets[n], end = offsets[n + 1];
    float acc = 0.f;
    int i = beg;
    for (; i + 4 <= end; i += 4) {
        int2 e0 = edges[i], e1 = edges[i + 1], e2 = edges[i + 2], e3 = edges[i + 3];
        float w0 = __builtin_bit_cast(float, e0.y);
        float w1 = __builtin_bit_cast(float, e1.y);
        float w2 = __builtin_bit_cast(float, e2.y);
        float w3 = __builtin_bit_cast(float, e3.y);
        if (lane < NCLASS) {
            float v0 = bf2f(S2b[(size_t)e0.x * NCLASS + lane]);
            float v1 = bf2f(S2b[(size_t)e1.x * NCLASS + lane]);
            float v2 = bf2f(S2b[(size_t)e2.x * NCLASS + lane]);
            float v3 = bf2f(S2b[(size_t)e3.x * NCLASS + lane]);
            acc += w0 * v0 + w1 * v1 + w2 * v2 + w3 * v3;
        }
    }
    for (; i < end; i++) {
        int2 e = edges[i];
        float ww = __builtin_bit_cast(float, e.y);
        if (lane < NCLASS) acc += ww * bf2f(S2b[(size_t)e.x * NCLASS + lane]);
    }
    float v = (lane < NCLASS) ? (acc + b2[lane]) : -INFINITY;
    float m = v;
#pragma unroll
    for (int off = 32; off > 0; off >>= 1) m = fmaxf(m, __shfl_xor(m, off));
    float ex = (lane < NCLASS) ? expf(v - m) : 0.f;
    float ssum = ex;
#pragma unroll
    for (int off = 32; off > 0; off >>= 1) ssum += __shfl_xor(ssum, off);
    if (lane < NCLASS) out[(size_t)n * NCLASS + lane] = v - m - logf(ssum);
}

extern "C" void kernel_launch(void* const* d_in, const int* in_sizes, int n_in,
                              void* d_out, int out_size, void* d_ws, size_t ws_size,
                              hipStream_t stream) {
    const float* x     = (const float*)d_in[0];
    const int*   esrc  = (const int*)d_in[1];
    const int*   edst  = (const int*)d_in[2];
    const float* ew    = (const float*)d_in[3];
    const float* eps   = (const float*)d_in[4];
    const float* W1    = (const float*)d_in[5];
    const float* b1    = (const float*)d_in[6];
    const float* W_mu  = (const float*)d_in[7];
    const float* b_mu  = (const float*)d_in[8];
    const float* W_lv  = (const float*)d_in[9];
    const float* b_lv  = (const float*)d_in[10];
    const float* W_dec = (const float*)d_in[11];
    const float* b_dec = (const float*)d_in[12];
    const float* W2    = (const float*)d_in[13];
    const float* b2    = (const float*)d_in[14];
    float* out = (float*)d_out;

    // workspace layout (counts & cursor adjacent -> single memset)
    unsigned short* support1b = (unsigned short*)d_ws;                     // 12.8M u16
    unsigned short* x1cat = support1b + (size_t)N_NODES * NHID;            // 25.6M u16
    unsigned short* S2b = x1cat + (size_t)N_NODES * 2 * NHID;              // 2M u16
    unsigned short* W1t    = S2b + (size_t)N_NODES * NCLASS;
    unsigned short* W2bt   = W1t + (size_t)NHID * NFEAT;
    unsigned short* W_mulvt = W2bt + (size_t)NCLS_PAD * NFEAT;
    unsigned short* W_dect  = W_mulvt + 128 * 256;
    int*   counts   = (int*)(((size_t)(W_dect + 256 * 64) + 3) & ~(size_t)3);
    int*   cursor   = counts + N_NODES;
    int*   offsets  = cursor + N_NODES;     // N+1
    int*   blockSums    = offsets + N_NODES + 1;   // NB_SCAN
    int*   blockOffsets = blockSums + NB_SCAN;     // NB_SCAN
    int2*  edges    = (int2*)(blockOffsets + NB_SCAN);
    edges = (int2*)(((size_t)edges + 7) & ~(size_t)7);
    size_t need = (size_t)((char*)(edges + N_EDGES) - (char*)d_ws);
    if (ws_size < need) return;

    hipMemsetAsync(counts, 0, 2 * N_NODES * sizeof(int), stream);  // counts + cursor
    hist_kernel<<<(N_EDGES + 255) / 256, 256, 0, stream>>>(edst, counts);
    scan_block_sums<<<NB_SCAN, 256, 0, stream>>>(counts, blockSums);
    scan_block_offsets<<<1, 256, 0, stream>>>(blockSums, blockOffsets, offsets);
    scan_final<<<NB_SCAN, 256, 0, stream>>>(counts, blockOffsets, offsets);
    scatter_kernel<<<(N_EDGES + 255) / 256, 256, 0, stream>>>(edst, esrc, ew, offsets, cursor,
                                                              edges);

    wprep_kernel<<<800, 256, 0, stream>>>(W1, W2, W_mu, W_lv, W_dec, W1t, W2bt, W_mulvt, W_dect);
    dim3 g1((N_NODES + 63) / 64, 2);
    gemm1_mfma<<<g1, 256, 0, stream>>>(x, W1t, support1b);
    spmm1_kernel<<<N_NODES / 4, 256, 0, stream>>>(offsets, edges, support1b, b1, x1cat);
    mlp_mfma<<<N_NODES / 16, 256, 0, stream>>>(x1cat, eps, b_mu, b_lv, W_mulvt, b_dec, W_dect,
                                               x1cat);
    gemm2_mfma<<<(N_NODES + 63) / 64, 256, 0, stream>>>(x1cat, W2bt, S2b);
    spmm2_softmax_kernel<<<N_NODES / 4, 256, 0, stream>>>(offsets, edges, S2b, b2, out);
}